// Round 8
// baseline (694.317 us; speedup 1.0000x reference)
//
#include <hip/hip_runtime.h>

#define N_NODES 50000
#define E_EDGES 800000
#define SCAN_NB 196   // 196*256 = 50176 >= N_NODES

// ============================ CSR build =====================================
__global__ __launch_bounds__(256) void k_hist(
    const int* __restrict__ ei, int* __restrict__ cnt)
{
    const int e = blockIdx.x * 256 + threadIdx.x;
    if (e < E_EDGES) atomicAdd(&cnt[ei[E_EDGES + e]], 1);
}

// ---- two-level parallel exclusive scan -------------------------------------
__global__ __launch_bounds__(256) void k_scan1(
    const int* __restrict__ cnt, int* __restrict__ bsum)
{
    __shared__ int red[256];
    const int tid = threadIdx.x;
    const int i = blockIdx.x * 256 + tid;
    red[tid] = (i < N_NODES) ? cnt[i] : 0;
    __syncthreads();
    for (int off = 128; off > 0; off >>= 1) {
        if (tid < off) red[tid] += red[tid + off];
        __syncthreads();
    }
    if (tid == 0) bsum[blockIdx.x] = red[0];
}

__global__ __launch_bounds__(256) void k_scan2(
    const int* __restrict__ bsum, int* __restrict__ boff)
{
    __shared__ int part[256];
    const int tid = threadIdx.x;
    const int v = (tid < SCAN_NB) ? bsum[tid] : 0;
    part[tid] = v;
    __syncthreads();
    for (int off = 1; off < 256; off <<= 1) {
        const int vv = part[tid];
        const int u = (tid >= off) ? part[tid - off] : 0;
        __syncthreads();
        part[tid] = vv + u;
        __syncthreads();
    }
    if (tid < SCAN_NB) boff[tid] = part[tid] - v;   // exclusive block offset
}

__global__ __launch_bounds__(256) void k_scan3(
    const int* __restrict__ cnt, const int* __restrict__ boff,
    int* __restrict__ rowptr, int* __restrict__ cursor)
{
    __shared__ int part[256];
    const int tid = threadIdx.x;
    const int i = blockIdx.x * 256 + tid;
    const int v = (i < N_NODES) ? cnt[i] : 0;
    part[tid] = v;
    __syncthreads();
    for (int off = 1; off < 256; off <<= 1) {
        const int vv = part[tid];
        const int u = (tid >= off) ? part[tid - off] : 0;
        __syncthreads();
        part[tid] = vv + u;
        __syncthreads();
    }
    const int excl = part[tid] - v + boff[blockIdx.x];
    if (i < N_NODES) { rowptr[i] = excl; cursor[i] = excl; }
    if (i == N_NODES) rowptr[N_NODES] = excl;  // beyond-end v=0 => excl = total
}

__global__ __launch_bounds__(256) void k_scatter(
    const int* __restrict__ ei, int* __restrict__ cursor, int2* __restrict__ pairs)
{
    const int e = blockIdx.x * 256 + threadIdx.x;
    if (e < E_EDGES) {
        const int dst = ei[E_EDGES + e];
        const int pos = atomicAdd(&cursor[dst], 1);
        pairs[pos] = make_int2(ei[e], e);
    }
}

// ============ CSR-order edge-attr pre-scale (kills gather deps) =============
__global__ __launch_bounds__(256) void k_prep(
    const int2* __restrict__ pairs, const float* __restrict__ eattr,
    const float* __restrict__ ew, float* __restrict__ eaw, int* __restrict__ srcs)
{
    const int t = blockIdx.x * 256 + threadIdx.x;
    const int pos = t >> 2;
    if (pos >= E_EDGES) return;
    const int q = t & 3;
    const int2 p = pairs[pos];
    if (q == 0) srcs[pos] = p.x;
    const float w = ew[p.y];
    const float4 a = *((const float4*)(eattr + (size_t)p.y * 16) + q);
    *((float4*)(eaw + (size_t)pos * 16) + q) =
        make_float4(a.x * w, a.y * w, a.z * w, a.w * w);
}

// ================== Weight transposes (once, tiny) ==========================
// WT segments (float offsets): WT11@0 [64][128], WT12@8192 [128][128],
// WT21@24576, WT22@40960, WTo@57344 [128][128] (j>=100 zero-padded),
// WeT1@73728 [16][64], WeT2@74752 [16][128].
__global__ __launch_bounds__(256) void k_wt(
    const float* __restrict__ W11, const float* __restrict__ W12,
    const float* __restrict__ W21, const float* __restrict__ W22,
    const float* __restrict__ Wo,
    const float* __restrict__ We1, const float* __restrict__ We2,
    float* __restrict__ WT)
{
    const int bid = blockIdx.x;
    const int tid = threadIdx.x;
    if (bid < 288) {
        const float* src; int KIN, JOUT, lbase, obase;
        if (bid < 32)       { src = W11; KIN = 64;  JOUT = 128; lbase = 0;   obase = 0; }
        else if (bid < 96)  { src = W12; KIN = 128; JOUT = 128; lbase = 32;  obase = 8192; }
        else if (bid < 160) { src = W21; KIN = 128; JOUT = 128; lbase = 96;  obase = 24576; }
        else if (bid < 224) { src = W22; KIN = 128; JOUT = 128; lbase = 160; obase = 40960; }
        else                { src = Wo;  KIN = 128; JOUT = 100; lbase = 224; obase = 57344; }
        const int idx = (bid - lbase) * 256 + tid;   // < KIN*128
        const int k = idx >> 7, j = idx & 127;
        WT[obase + idx] = (j < JOUT) ? src[j * KIN + k] : 0.f;
    } else if (bid < 292) {                   // WeT1[k][d] = We1[d][k]
        const int idx = (bid - 288) * 256 + tid;     // < 1024
        const int k = idx >> 6, d = idx & 63;
        WT[73728 + idx] = We1[d * 16 + k];
    } else {                                  // WeT2[k][d] = We2[d][k]
        const int idx = (bid - 292) * 256 + tid;     // < 2048
        const int k = idx >> 7, d = idx & 127;
        WT[74752 + idx] = We2[d * 16 + k];
    }
}

// ===================== Edge layer 1 (CSR gather, 16->64) ====================
// One wave per node; node wave-uniform (readfirstlane) so rp/srcs/eaw reads
// are s_load through the scalar pipe. 16 FMA + coalesced x-row read per edge.
__global__ __launch_bounds__(256, 4) void k_edge1(
    const int* __restrict__ rp, const int* __restrict__ srcs,
    const float* __restrict__ eaw,
    const float* __restrict__ WeT1, const float* __restrict__ be1,
    const float* __restrict__ x, float* __restrict__ out)
{
    const int lane = threadIdx.x & 63;
    const int node =
        __builtin_amdgcn_readfirstlane(blockIdx.x * 4 + (threadIdx.x >> 6));
    if (node >= N_NODES) return;

    float wr[16];
#pragma unroll
    for (int k = 0; k < 16; ++k) wr[k] = WeT1[k * 64 + lane];   // coalesced 256B
    const float bias = be1[lane];

    const int beg = rp[node], end = rp[node + 1];               // s_load
    float acc = 0.f;

#pragma unroll 4
    for (int c = beg; c < end; ++c) {
        const int src = srcs[c];                     // uniform -> s_load
        const float hv = x[(size_t)src * 64 + lane]; // coalesced row read
        const float* ep = eaw + (size_t)c * 16;      // uniform -> s_load x16
        float d = bias;
#pragma unroll
        for (int k = 0; k < 16; ++k) d = fmaf(ep[k], wr[k], d);
        acc += fmaxf(hv + d, 0.f);
    }
    out[(size_t)node * 64 + lane] = x[(size_t)node * 64 + lane] + acc;
}

// ===================== Edge layer 2 (CSR gather, 16->128) ===================
__global__ __launch_bounds__(256, 4) void k_edge2(
    const int* __restrict__ rp, const int* __restrict__ srcs,
    const float* __restrict__ eaw,
    const float* __restrict__ WeT2, const float* __restrict__ be2,
    const float* __restrict__ h, float* __restrict__ out)
{
    const int lane = threadIdx.x & 63;
    const int node =
        __builtin_amdgcn_readfirstlane(blockIdx.x * 4 + (threadIdx.x >> 6));
    if (node >= N_NODES) return;

    const int dA = 2 * lane;
    float wrA[16], wrB[16];
#pragma unroll
    for (int k = 0; k < 16; ++k) {
        const float2 w = *(const float2*)(WeT2 + k * 128 + dA);  // coalesced 512B
        wrA[k] = w.x; wrB[k] = w.y;
    }
    const float2 bv = *(const float2*)(be2 + dA);
    const float biasA = bv.x, biasB = bv.y;

    const int beg = rp[node], end = rp[node + 1];                // s_load
    float accA = 0.f, accB = 0.f;

    const float* hrow = h + dA;

#pragma unroll 4
    for (int c = beg; c < end; ++c) {
        const int src = srcs[c];                      // uniform -> s_load
        const float2 hv = *(const float2*)(hrow + (size_t)src * 128);
        const float* ep = eaw + (size_t)c * 16;       // uniform -> s_load x16
        float dA_ = biasA, dB_ = biasB;
#pragma unroll
        for (int k = 0; k < 16; ++k) {
            dA_ = fmaf(ep[k], wrA[k], dA_);
            dB_ = fmaf(ep[k], wrB[k], dB_);
        }
        accA += fmaxf(hv.x + dA_, 0.f);
        accB += fmaxf(hv.y + dB_, 0.f);
    }
    const float2 self = *(const float2*)(h + (size_t)node * 128 + dA);
    *(float2*)(out + (size_t)node * 128 + dA) =
        make_float2(self.x + accA, self.y + accB);
}

// ==================== Fused MLP chains (LDS-resident h) =====================
// Per stage: lane owns one node (NT=64/block), wave owns j0=wv*32..+31
// (wave-uniform -> W rows + bias via s_load). Per k: 1 conflict-free
// ds_read + 32 FMA. Weight double-buffer via 2-step k loop (no reg copies).
// Inter-stage activations stay in LDS [128][65] (pad 65: lane-consecutive
// reads/writes conflict-free). No global round trip between layers.

template<int KIN>
__device__ __forceinline__ void gstage(
    const float* __restrict__ WTb, int j0,
    const float* S, int lane, float acc[32])
{
#pragma unroll
    for (int m = 0; m < 32; ++m) acc[m] = 0.f;
    float wA[32], wB[32];
#pragma unroll
    for (int m = 0; m < 32; ++m) wA[m] = WTb[j0 + m];     // s_load (uniform)
    float hA = S[lane];
    for (int k = 0; k < KIN; k += 2) {
#pragma unroll
        for (int m = 0; m < 32; ++m) wB[m] = WTb[(k + 1) * 128 + j0 + m];
        const float hB = S[(k + 1) * 65 + lane];
#pragma unroll
        for (int m = 0; m < 32; ++m) acc[m] = fmaf(hA, wA[m], acc[m]);
        if (k + 2 < KIN) {
#pragma unroll
            for (int m = 0; m < 32; ++m) wA[m] = WTb[(k + 2) * 128 + j0 + m];
            hA = S[(k + 2) * 65 + lane];
        }
#pragma unroll
        for (int m = 0; m < 32; ++m) acc[m] = fmaf(hB, wB[m], acc[m]);
    }
}

// Stage a 64-node tile of H (row-major, KIN cols) transposed into S[KIN][65].
template<int KIN>
__device__ __forceinline__ void stage_tile(
    const float* __restrict__ H, int base, int tid, float* S)
{
    for (int idx = tid; idx < 64 * (KIN / 4); idx += 256) {
        const int q = idx & (KIN / 4 - 1);
        const int n = idx / (KIN / 4);
        const int ng = (base + n < N_NODES) ? (base + n) : (N_NODES - 1);
        const float4 v = *(const float4*)(H + (size_t)ng * KIN + 4 * q);
        S[(4 * q + 0) * 65 + n] = v.x;
        S[(4 * q + 1) * 65 + n] = v.y;
        S[(4 * q + 2) * 65 + n] = v.z;
        S[(4 * q + 3) * 65 + n] = v.w;
    }
}

// h1pre(64) -> relu(W11) -> relu(W12) -> t1(128)
__global__ __launch_bounds__(256) void k_mlp2(
    const float* __restrict__ H, const float* __restrict__ WT11,
    const float* __restrict__ b11, const float* __restrict__ WT12,
    const float* __restrict__ b12, float* __restrict__ OUT)
{
    extern __shared__ float lds[];
    float* A = lds;             // [64][65]
    float* B = lds + 64 * 65;   // [128][65]
    const int tid  = threadIdx.x;
    const int lane = tid & 63;
    const int j0   = __builtin_amdgcn_readfirstlane(tid >> 6) * 32;
    const int base = blockIdx.x * 64;

    stage_tile<64>(H, base, tid, A);
    __syncthreads();

    float acc[32];
    gstage<64>(WT11, j0, A, lane, acc);
#pragma unroll
    for (int m = 0; m < 32; ++m)
        B[(j0 + m) * 65 + lane] = fmaxf(acc[m] + b11[j0 + m], 0.f);
    __syncthreads();

    gstage<128>(WT12, j0, B, lane, acc);

    const int node = base + lane;
    if (node < N_NODES) {
        float* row = OUT + (size_t)node * 128 + j0;
#pragma unroll
        for (int g = 0; g < 8; ++g) {
            float4 v;
            v.x = fmaxf(acc[4 * g + 0] + b12[j0 + 4 * g + 0], 0.f);
            v.y = fmaxf(acc[4 * g + 1] + b12[j0 + 4 * g + 1], 0.f);
            v.z = fmaxf(acc[4 * g + 2] + b12[j0 + 4 * g + 2], 0.f);
            v.w = fmaxf(acc[4 * g + 3] + b12[j0 + 4 * g + 3], 0.f);
            *(float4*)(row + 4 * g) = v;
        }
    }
}

// h2pre(128) -> relu(W21) -> relu(W22) -> Wo -> out(100)
__global__ __launch_bounds__(256) void k_mlp3(
    const float* __restrict__ H, const float* __restrict__ WT21,
    const float* __restrict__ b21, const float* __restrict__ WT22,
    const float* __restrict__ b22, const float* __restrict__ WTo,
    const float* __restrict__ bo, float* __restrict__ OUT)
{
    extern __shared__ float lds[];
    float* A = lds;              // [128][65]
    float* B = lds + 128 * 65;   // [128][65]
    const int tid  = threadIdx.x;
    const int lane = tid & 63;
    const int j0   = __builtin_amdgcn_readfirstlane(tid >> 6) * 32;
    const int base = blockIdx.x * 64;

    stage_tile<128>(H, base, tid, A);
    __syncthreads();

    float acc[32];
    gstage<128>(WT21, j0, A, lane, acc);
#pragma unroll
    for (int m = 0; m < 32; ++m)
        B[(j0 + m) * 65 + lane] = fmaxf(acc[m] + b21[j0 + m], 0.f);
    __syncthreads();

    gstage<128>(WT22, j0, B, lane, acc);      // A dead; reuse as t2
    __syncthreads();                          // all reads of B done
#pragma unroll
    for (int m = 0; m < 32; ++m)
        A[(j0 + m) * 65 + lane] = fmaxf(acc[m] + b22[j0 + m], 0.f);
    __syncthreads();

    gstage<128>(WTo, j0, A, lane, acc);

    const int node = base + lane;
    if (node < N_NODES) {
        float* row = OUT + (size_t)node * 100;
#pragma unroll
        for (int g = 0; g < 8; ++g) {
            if (j0 + 4 * g < 100) {           // 100%4==0: full groups only
                float4 v;
                v.x = acc[4 * g + 0] + bo[j0 + 4 * g + 0];
                v.y = acc[4 * g + 1] + bo[j0 + 4 * g + 1];
                v.z = acc[4 * g + 2] + bo[j0 + 4 * g + 2];
                v.w = acc[4 * g + 3] + bo[j0 + 4 * g + 3];
                *(float4*)(row + j0 + 4 * g) = v;
            }
        }
    }
}

// ============================================================================
// Workspace layout (peak 106,118,144 B), lifetimes packed:
//   [0,        204800)  rowptr            (build .. edge2)
//   [204800,  3404800)  srcs              (prep .. edge2)
//       cnt    @204800  (hist..scan, dead before srcs written)
//       cursor @409600  (scan..scatter, dead before srcs written)
//   [3404800, 54604800) eaw  51.2MB       (prep .. edge2)
//   [54604800,80204800) t1 (=h1) 25.6MB   (mlp2 .. edge2-in)
//       pairs @54604800 6.4MB             (scatter..prep, dead before t1)
//   [80204800,105804800) h2pre 25.6MB     (edge2-out .. mlp3)
//       h1pre @80204800 12.8MB            (edge1..mlp2, dead before h2pre)
//   [105804800,106116096) WT 311,296 B    (k_wt .. mlp3; incl WeT1/WeT2)
//   [106116096,106118144) bsum/boff 2KB   (scan only)
extern "C" void kernel_launch(void* const* d_in, const int* in_sizes, int n_in,
                              void* d_out, int out_size, void* d_ws, size_t ws_size,
                              hipStream_t stream) {
    const float* x     = (const float*)d_in[0];
    const int*   ei    = (const int*)  d_in[1];
    const float* eattr = (const float*)d_in[2];
    const float* ew    = (const float*)d_in[3];
    const float* We1   = (const float*)d_in[4];
    const float* be1   = (const float*)d_in[5];
    const float* W11   = (const float*)d_in[6];
    const float* b11   = (const float*)d_in[7];
    const float* W12   = (const float*)d_in[8];
    const float* b12   = (const float*)d_in[9];
    const float* We2   = (const float*)d_in[10];
    const float* be2   = (const float*)d_in[11];
    const float* W21   = (const float*)d_in[12];
    const float* b21   = (const float*)d_in[13];
    const float* W22   = (const float*)d_in[14];
    const float* b22   = (const float*)d_in[15];
    const float* Wo    = (const float*)d_in[16];
    const float* bo    = (const float*)d_in[17];
    float* out = (float*)d_out;

    char* ws = (char*)d_ws;
    int*   rowptr = (int*)  (ws + 0);
    int*   cnt    = (int*)  (ws + 204800);
    int*   cursor = (int*)  (ws + 409600);
    int*   srcs   = (int*)  (ws + 204800);     // overlays cnt+cursor (dead)
    float* eaw    = (float*)(ws + 3404800);    // 51.2 MB
    float* t1     = (float*)(ws + 54604800);   // 25.6 MB (h1 alias)
    int2*  pairs  = (int2*) (ws + 54604800);   // 6.4 MB, dead before t1 written
    float* h2pre  = (float*)(ws + 80204800);   // 25.6 MB
    float* h1pre  = (float*)(ws + 80204800);   // 12.8 MB, dead before h2pre
    float* WT     = (float*)(ws + 105804800);  // 311,296 B
    float* WT11 = WT;           // [64][128]
    float* WT12 = WT + 8192;    // [128][128]
    float* WT21 = WT + 24576;
    float* WT22 = WT + 40960;
    float* WTo  = WT + 57344;   // [128][128] zero-padded j>=100
    float* WeT1 = WT + 73728;   // [16][64]
    float* WeT2 = WT + 74752;   // [16][128]
    int*   bsum = (int*)(ws + 106116096);      // 196 ints (pad 1KB)
    int*   boff = (int*)(ws + 106117120);      // 196 ints

    hipMemsetAsync(cnt, 0, 200000, stream);

    k_wt<<<300, 256, 0, stream>>>(W11, W12, W21, W22, Wo, We1, We2, WT);

    const int EB = (E_EDGES + 255) / 256;      // 3125
    k_hist<<<EB, 256, 0, stream>>>(ei, cnt);
    k_scan1<<<SCAN_NB, 256, 0, stream>>>(cnt, bsum);
    k_scan2<<<1, 256, 0, stream>>>(bsum, boff);
    k_scan3<<<SCAN_NB, 256, 0, stream>>>(cnt, boff, rowptr, cursor);
    k_scatter<<<EB, 256, 0, stream>>>(ei, cursor, pairs);

    const int PB = (E_EDGES * 4 + 255) / 256;  // 12500
    k_prep<<<PB, 256, 0, stream>>>(pairs, eattr, ew, eaw, srcs);

    const int NB = (N_NODES + 3) / 4;          // 12500 (one wave per node)
    k_edge1<<<NB, 256, 0, stream>>>(rowptr, srcs, eaw, WeT1, be1, x, h1pre);

    const int MB = (N_NODES + 63) / 64;                 // 782
    const size_t ldsA = (size_t)(64 * 65 + 128 * 65) * 4;    // 49,920 B
    const size_t ldsB = (size_t)(128 * 65 + 128 * 65) * 4;   // 66,560 B

    k_mlp2<<<MB, 256, ldsA, stream>>>(h1pre, WT11, b11, WT12, b12, t1);

    k_edge2<<<NB, 256, 0, stream>>>(rowptr, srcs, eaw, WeT2, be2, t1, h2pre);

    k_mlp3<<<MB, 256, ldsB, stream>>>(h2pre, WT21, b21, WT22, b22, WTo, bo, out);
}

// Round 9
// 550.862 us; speedup vs baseline: 1.2604x; 1.2604x over previous
//
#include <hip/hip_runtime.h>

#define N_NODES 50000
#define E_EDGES 800000
#define SCAN_NB 196   // 196*256 = 50176 >= N_NODES

// ============================ CSR build =====================================
__global__ __launch_bounds__(256) void k_hist(
    const int* __restrict__ ei, int* __restrict__ cnt)
{
    const int e = blockIdx.x * 256 + threadIdx.x;
    if (e < E_EDGES) atomicAdd(&cnt[ei[E_EDGES + e]], 1);
}

// ---- two-level parallel exclusive scan -------------------------------------
__global__ __launch_bounds__(256) void k_scan1(
    const int* __restrict__ cnt, int* __restrict__ bsum)
{
    __shared__ int red[256];
    const int tid = threadIdx.x;
    const int i = blockIdx.x * 256 + tid;
    red[tid] = (i < N_NODES) ? cnt[i] : 0;
    __syncthreads();
    for (int off = 128; off > 0; off >>= 1) {
        if (tid < off) red[tid] += red[tid + off];
        __syncthreads();
    }
    if (tid == 0) bsum[blockIdx.x] = red[0];
}

__global__ __launch_bounds__(256) void k_scan2(
    const int* __restrict__ bsum, int* __restrict__ boff)
{
    __shared__ int part[256];
    const int tid = threadIdx.x;
    const int v = (tid < SCAN_NB) ? bsum[tid] : 0;
    part[tid] = v;
    __syncthreads();
    for (int off = 1; off < 256; off <<= 1) {
        const int vv = part[tid];
        const int u = (tid >= off) ? part[tid - off] : 0;
        __syncthreads();
        part[tid] = vv + u;
        __syncthreads();
    }
    if (tid < SCAN_NB) boff[tid] = part[tid] - v;   // exclusive block offset
}

__global__ __launch_bounds__(256) void k_scan3(
    const int* __restrict__ cnt, const int* __restrict__ boff,
    int* __restrict__ rowptr, int* __restrict__ cursor)
{
    __shared__ int part[256];
    const int tid = threadIdx.x;
    const int i = blockIdx.x * 256 + tid;
    const int v = (i < N_NODES) ? cnt[i] : 0;
    part[tid] = v;
    __syncthreads();
    for (int off = 1; off < 256; off <<= 1) {
        const int vv = part[tid];
        const int u = (tid >= off) ? part[tid - off] : 0;
        __syncthreads();
        part[tid] = vv + u;
        __syncthreads();
    }
    const int excl = part[tid] - v + boff[blockIdx.x];
    if (i < N_NODES) { rowptr[i] = excl; cursor[i] = excl; }
    if (i == N_NODES) rowptr[N_NODES] = excl;  // beyond-end v=0 => excl = total
}

__global__ __launch_bounds__(256) void k_scatter(
    const int* __restrict__ ei, int* __restrict__ cursor, int2* __restrict__ pairs)
{
    const int e = blockIdx.x * 256 + threadIdx.x;
    if (e < E_EDGES) {
        const int dst = ei[E_EDGES + e];
        const int pos = atomicAdd(&cursor[dst], 1);
        pairs[pos] = make_int2(ei[e], e);
    }
}

// ============ CSR-order edge-attr pre-scale (kills gather deps) =============
__global__ __launch_bounds__(256) void k_prep(
    const int2* __restrict__ pairs, const float* __restrict__ eattr,
    const float* __restrict__ ew, float* __restrict__ eaw, int* __restrict__ srcs)
{
    const int t = blockIdx.x * 256 + threadIdx.x;
    const int pos = t >> 2;
    if (pos >= E_EDGES) return;
    const int q = t & 3;
    const int2 p = pairs[pos];
    if (q == 0) srcs[pos] = p.x;
    const float w = ew[p.y];
    const float4 a = *((const float4*)(eattr + (size_t)p.y * 16) + q);
    *((float4*)(eaw + (size_t)pos * 16) + q) =
        make_float4(a.x * w, a.y * w, a.z * w, a.w * w);
}

// ================== Weight transposes (once, tiny) ==========================
// WT segments (float offsets): WT11@0 [64][128], WT12@8192 [128][128],
// WT21@24576, WT22@40960, WTo@57344 [128][128] (j>=100 zero-padded),
// WeT1@73728 [16][64], WeT2@74752 [16][128].
__global__ __launch_bounds__(256) void k_wt(
    const float* __restrict__ W11, const float* __restrict__ W12,
    const float* __restrict__ W21, const float* __restrict__ W22,
    const float* __restrict__ Wo,
    const float* __restrict__ We1, const float* __restrict__ We2,
    float* __restrict__ WT)
{
    const int bid = blockIdx.x;
    const int tid = threadIdx.x;
    if (bid < 288) {
        const float* src; int KIN, JOUT, lbase, obase;
        if (bid < 32)       { src = W11; KIN = 64;  JOUT = 128; lbase = 0;   obase = 0; }
        else if (bid < 96)  { src = W12; KIN = 128; JOUT = 128; lbase = 32;  obase = 8192; }
        else if (bid < 160) { src = W21; KIN = 128; JOUT = 128; lbase = 96;  obase = 24576; }
        else if (bid < 224) { src = W22; KIN = 128; JOUT = 128; lbase = 160; obase = 40960; }
        else                { src = Wo;  KIN = 128; JOUT = 100; lbase = 224; obase = 57344; }
        const int idx = (bid - lbase) * 256 + tid;   // < KIN*128
        const int k = idx >> 7, j = idx & 127;
        WT[obase + idx] = (j < JOUT) ? src[j * KIN + k] : 0.f;
    } else if (bid < 292) {                   // WeT1[k][d] = We1[d][k]
        const int idx = (bid - 288) * 256 + tid;     // < 1024
        const int k = idx >> 6, d = idx & 63;
        WT[73728 + idx] = We1[d * 16 + k];
    } else {                                  // WeT2[k][d] = We2[d][k]
        const int idx = (bid - 292) * 256 + tid;     // < 2048
        const int k = idx >> 7, d = idx & 127;
        WT[74752 + idx] = We2[d * 16 + k];
    }
}

// ===================== Edge layer 1 (CSR gather, 16->64) ====================
// One wave per node; node wave-uniform (readfirstlane) so rp/srcs/eaw reads
// are s_load through the scalar pipe. 16 FMA + coalesced x-row read per edge.
__global__ __launch_bounds__(256, 4) void k_edge1(
    const int* __restrict__ rp, const int* __restrict__ srcs,
    const float* __restrict__ eaw,
    const float* __restrict__ WeT1, const float* __restrict__ be1,
    const float* __restrict__ x, float* __restrict__ out)
{
    const int lane = threadIdx.x & 63;
    const int node =
        __builtin_amdgcn_readfirstlane(blockIdx.x * 4 + (threadIdx.x >> 6));
    if (node >= N_NODES) return;

    float wr[16];
#pragma unroll
    for (int k = 0; k < 16; ++k) wr[k] = WeT1[k * 64 + lane];   // coalesced 256B
    const float bias = be1[lane];

    const int beg = rp[node], end = rp[node + 1];               // s_load
    float acc = 0.f;

#pragma unroll 4
    for (int c = beg; c < end; ++c) {
        const int src = srcs[c];                     // uniform -> s_load
        const float hv = x[(size_t)src * 64 + lane]; // coalesced row read
        const float* ep = eaw + (size_t)c * 16;      // uniform -> s_load x16
        float d = bias;
#pragma unroll
        for (int k = 0; k < 16; ++k) d = fmaf(ep[k], wr[k], d);
        acc += fmaxf(hv + d, 0.f);
    }
    out[(size_t)node * 64 + lane] = x[(size_t)node * 64 + lane] + acc;
}

// ===================== Edge layer 2 (CSR gather, 16->128) ===================
__global__ __launch_bounds__(256, 4) void k_edge2(
    const int* __restrict__ rp, const int* __restrict__ srcs,
    const float* __restrict__ eaw,
    const float* __restrict__ WeT2, const float* __restrict__ be2,
    const float* __restrict__ h, float* __restrict__ out)
{
    const int lane = threadIdx.x & 63;
    const int node =
        __builtin_amdgcn_readfirstlane(blockIdx.x * 4 + (threadIdx.x >> 6));
    if (node >= N_NODES) return;

    const int dA = 2 * lane;
    float wrA[16], wrB[16];
#pragma unroll
    for (int k = 0; k < 16; ++k) {
        const float2 w = *(const float2*)(WeT2 + k * 128 + dA);  // coalesced 512B
        wrA[k] = w.x; wrB[k] = w.y;
    }
    const float2 bv = *(const float2*)(be2 + dA);
    const float biasA = bv.x, biasB = bv.y;

    const int beg = rp[node], end = rp[node + 1];                // s_load
    float accA = 0.f, accB = 0.f;

    const float* hrow = h + dA;

#pragma unroll 4
    for (int c = beg; c < end; ++c) {
        const int src = srcs[c];                      // uniform -> s_load
        const float2 hv = *(const float2*)(hrow + (size_t)src * 128);
        const float* ep = eaw + (size_t)c * 16;       // uniform -> s_load x16
        float dA_ = biasA, dB_ = biasB;
#pragma unroll
        for (int k = 0; k < 16; ++k) {
            dA_ = fmaf(ep[k], wrA[k], dA_);
            dB_ = fmaf(ep[k], wrB[k], dB_);
        }
        accA += fmaxf(hv.x + dA_, 0.f);
        accB += fmaxf(hv.y + dB_, 0.f);
    }
    const float2 self = *(const float2*)(h + (size_t)node * 128 + dA);
    *(float2*)(out + (size_t)node * 128 + dA) =
        make_float2(self.x + accA, self.y + accB);
}

// ==================== Fused MLP chains (LDS-resident h) =====================
// R8 failure analysis: helper-function (gstage) packaging caused acc[32] to
// spill to scratch (VGPR_Count=24). Fix: stage loops written INLINE in kernel
// scope, exactly mirroring R7's proven k_mlp codegen (local acc[32], wc/wn
// double-buffer from wave-uniform WT addresses -> s_load, step-1 k loop).
// Lane owns 1 node (64/block), wave owns j0..j0+31. LDS tiles [*][65]
// (lane-consecutive reads/writes conflict-free).

#define MLP_STAGE(WTb, Bb, KIN, SRC, ACC)                                     \
    {                                                                         \
        _Pragma("unroll")                                                     \
        for (int m = 0; m < 32; ++m) ACC[m] = 0.f;                            \
        float wc[32];                                                         \
        _Pragma("unroll")                                                     \
        for (int m = 0; m < 32; ++m) wc[m] = WTb[j0 + m];                     \
        float h0 = SRC[lane];                                                 \
        for (int k = 0; k < (KIN) - 1; ++k) {                                 \
            float wn[32];                                                     \
            _Pragma("unroll")                                                 \
            for (int m = 0; m < 32; ++m) wn[m] = WTb[(k + 1) * 128 + j0 + m]; \
            const float h0n = SRC[(k + 1) * 65 + lane];                       \
            _Pragma("unroll")                                                 \
            for (int m = 0; m < 32; ++m) ACC[m] = fmaf(h0, wc[m], ACC[m]);    \
            _Pragma("unroll")                                                 \
            for (int m = 0; m < 32; ++m) wc[m] = wn[m];                       \
            h0 = h0n;                                                         \
        }                                                                     \
        _Pragma("unroll")                                                     \
        for (int m = 0; m < 32; ++m) ACC[m] = fmaf(h0, wc[m], ACC[m]);        \
    }

#define MLP_TILE(H, KIN, S)                                                   \
    for (int idx = tid; idx < 64 * ((KIN) / 4); idx += 256) {                 \
        const int q = idx & ((KIN) / 4 - 1);                                  \
        const int n = idx / ((KIN) / 4);                                      \
        const int ng = (base + n < N_NODES) ? (base + n) : (N_NODES - 1);     \
        const float4 v = *(const float4*)(H + (size_t)ng * (KIN) + 4 * q);    \
        S[(4 * q + 0) * 65 + n] = v.x;                                        \
        S[(4 * q + 1) * 65 + n] = v.y;                                        \
        S[(4 * q + 2) * 65 + n] = v.z;                                        \
        S[(4 * q + 3) * 65 + n] = v.w;                                        \
    }

// h1pre(64) -> relu(W11) -> relu(W12) -> t1(128)
__global__ __launch_bounds__(256) void k_mlp2(
    const float* __restrict__ H, const float* __restrict__ WT11,
    const float* __restrict__ b11, const float* __restrict__ WT12,
    const float* __restrict__ b12, float* __restrict__ OUT)
{
    extern __shared__ float lds[];
    float* A = lds;             // [64][65]
    float* B = lds + 64 * 65;   // [128][65]
    const int tid  = threadIdx.x;
    const int lane = tid & 63;
    const int j0   = __builtin_amdgcn_readfirstlane(tid >> 6) * 32;
    const int base = blockIdx.x * 64;

    MLP_TILE(H, 64, A);
    __syncthreads();

    float acc[32];
    MLP_STAGE(WT11, b11, 64, A, acc);
#pragma unroll
    for (int m = 0; m < 32; ++m)
        B[(j0 + m) * 65 + lane] = fmaxf(acc[m] + b11[j0 + m], 0.f);
    __syncthreads();

    MLP_STAGE(WT12, b12, 128, B, acc);

    const int node = base + lane;
    if (node < N_NODES) {
        float* row = OUT + (size_t)node * 128 + j0;
#pragma unroll
        for (int g = 0; g < 8; ++g) {
            float4 v;
            v.x = fmaxf(acc[4 * g + 0] + b12[j0 + 4 * g + 0], 0.f);
            v.y = fmaxf(acc[4 * g + 1] + b12[j0 + 4 * g + 1], 0.f);
            v.z = fmaxf(acc[4 * g + 2] + b12[j0 + 4 * g + 2], 0.f);
            v.w = fmaxf(acc[4 * g + 3] + b12[j0 + 4 * g + 3], 0.f);
            *(float4*)(row + 4 * g) = v;
        }
    }
}

// h2pre(128) -> relu(W21) -> relu(W22) -> Wo -> out(100)
__global__ __launch_bounds__(256) void k_mlp3(
    const float* __restrict__ H, const float* __restrict__ WT21,
    const float* __restrict__ b21, const float* __restrict__ WT22,
    const float* __restrict__ b22, const float* __restrict__ WTo,
    const float* __restrict__ bo, float* __restrict__ OUT)
{
    extern __shared__ float lds[];
    float* A = lds;              // [128][65]
    float* B = lds + 128 * 65;   // [128][65]
    const int tid  = threadIdx.x;
    const int lane = tid & 63;
    const int j0   = __builtin_amdgcn_readfirstlane(tid >> 6) * 32;
    const int base = blockIdx.x * 64;

    MLP_TILE(H, 128, A);
    __syncthreads();

    float acc[32];
    MLP_STAGE(WT21, b21, 128, A, acc);
#pragma unroll
    for (int m = 0; m < 32; ++m)
        B[(j0 + m) * 65 + lane] = fmaxf(acc[m] + b21[j0 + m], 0.f);
    __syncthreads();

    MLP_STAGE(WT22, b22, 128, B, acc);
    __syncthreads();                          // all reads of A done; reuse as t2
#pragma unroll
    for (int m = 0; m < 32; ++m)
        A[(j0 + m) * 65 + lane] = fmaxf(acc[m] + b22[j0 + m], 0.f);
    __syncthreads();

    MLP_STAGE(WTo, bo, 128, A, acc);

    const int node = base + lane;
    if (node < N_NODES) {
        float* row = OUT + (size_t)node * 100;
#pragma unroll
        for (int g = 0; g < 8; ++g) {
            if (j0 + 4 * g < 100) {           // 100%4==0: full groups only
                float4 v;
                v.x = acc[4 * g + 0] + bo[j0 + 4 * g + 0];
                v.y = acc[4 * g + 1] + bo[j0 + 4 * g + 1];
                v.z = acc[4 * g + 2] + bo[j0 + 4 * g + 2];
                v.w = acc[4 * g + 3] + bo[j0 + 4 * g + 3];
                *(float4*)(row + j0 + 4 * g) = v;
            }
        }
    }
}

// ============================================================================
// Workspace layout (peak 106,118,144 B), lifetimes packed:
//   [0,        204800)  rowptr            (build .. edge2)
//   [204800,  3404800)  srcs              (prep .. edge2)
//       cnt    @204800  (hist..scan, dead before srcs written)
//       cursor @409600  (scan..scatter, dead before srcs written)
//   [3404800, 54604800) eaw  51.2MB       (prep .. edge2)
//   [54604800,80204800) t1 (=h1) 25.6MB   (mlp2 .. edge2-in)
//       pairs @54604800 6.4MB             (scatter..prep, dead before t1)
//   [80204800,105804800) h2pre 25.6MB     (edge2-out .. mlp3)
//       h1pre @80204800 12.8MB            (edge1..mlp2, dead before h2pre)
//   [105804800,106116096) WT 311,296 B    (k_wt .. mlp3; incl WeT1/WeT2)
//   [106116096,106118144) bsum/boff 2KB   (scan only)
extern "C" void kernel_launch(void* const* d_in, const int* in_sizes, int n_in,
                              void* d_out, int out_size, void* d_ws, size_t ws_size,
                              hipStream_t stream) {
    const float* x     = (const float*)d_in[0];
    const int*   ei    = (const int*)  d_in[1];
    const float* eattr = (const float*)d_in[2];
    const float* ew    = (const float*)d_in[3];
    const float* We1   = (const float*)d_in[4];
    const float* be1   = (const float*)d_in[5];
    const float* W11   = (const float*)d_in[6];
    const float* b11   = (const float*)d_in[7];
    const float* W12   = (const float*)d_in[8];
    const float* b12   = (const float*)d_in[9];
    const float* We2   = (const float*)d_in[10];
    const float* be2   = (const float*)d_in[11];
    const float* W21   = (const float*)d_in[12];
    const float* b21   = (const float*)d_in[13];
    const float* W22   = (const float*)d_in[14];
    const float* b22   = (const float*)d_in[15];
    const float* Wo    = (const float*)d_in[16];
    const float* bo    = (const float*)d_in[17];
    float* out = (float*)d_out;

    char* ws = (char*)d_ws;
    int*   rowptr = (int*)  (ws + 0);
    int*   cnt    = (int*)  (ws + 204800);
    int*   cursor = (int*)  (ws + 409600);
    int*   srcs   = (int*)  (ws + 204800);     // overlays cnt+cursor (dead)
    float* eaw    = (float*)(ws + 3404800);    // 51.2 MB
    float* t1     = (float*)(ws + 54604800);   // 25.6 MB (h1 alias)
    int2*  pairs  = (int2*) (ws + 54604800);   // 6.4 MB, dead before t1 written
    float* h2pre  = (float*)(ws + 80204800);   // 25.6 MB
    float* h1pre  = (float*)(ws + 80204800);   // 12.8 MB, dead before h2pre
    float* WT     = (float*)(ws + 105804800);  // 311,296 B
    float* WT11 = WT;           // [64][128]
    float* WT12 = WT + 8192;    // [128][128]
    float* WT21 = WT + 24576;
    float* WT22 = WT + 40960;
    float* WTo  = WT + 57344;   // [128][128] zero-padded j>=100
    float* WeT1 = WT + 73728;   // [16][64]
    float* WeT2 = WT + 74752;   // [16][128]
    int*   bsum = (int*)(ws + 106116096);      // 196 ints (pad 1KB)
    int*   boff = (int*)(ws + 106117120);      // 196 ints

    hipMemsetAsync(cnt, 0, 200000, stream);

    k_wt<<<300, 256, 0, stream>>>(W11, W12, W21, W22, Wo, We1, We2, WT);

    const int EB = (E_EDGES + 255) / 256;      // 3125
    k_hist<<<EB, 256, 0, stream>>>(ei, cnt);
    k_scan1<<<SCAN_NB, 256, 0, stream>>>(cnt, bsum);
    k_scan2<<<1, 256, 0, stream>>>(bsum, boff);
    k_scan3<<<SCAN_NB, 256, 0, stream>>>(cnt, boff, rowptr, cursor);
    k_scatter<<<EB, 256, 0, stream>>>(ei, cursor, pairs);

    const int PB = (E_EDGES * 4 + 255) / 256;  // 12500
    k_prep<<<PB, 256, 0, stream>>>(pairs, eattr, ew, eaw, srcs);

    const int NB = (N_NODES + 3) / 4;          // 12500 (one wave per node)
    k_edge1<<<NB, 256, 0, stream>>>(rowptr, srcs, eaw, WeT1, be1, x, h1pre);

    const int MB = (N_NODES + 63) / 64;                      // 782
    const size_t ldsA = (size_t)(64 * 65 + 128 * 65) * 4;    // 49,920 B
    const size_t ldsB = (size_t)(128 * 65 + 128 * 65) * 4;   // 66,560 B

    k_mlp2<<<MB, 256, ldsA, stream>>>(h1pre, WT11, b11, WT12, b12, t1);

    k_edge2<<<NB, 256, 0, stream>>>(rowptr, srcs, eaw, WeT2, be2, t1, h2pre);

    k_mlp3<<<MB, 256, ldsB, stream>>>(h2pre, WT21, b21, WT22, b22, WTo, bo, out);
}

// Round 10
// 524.916 us; speedup vs baseline: 1.3227x; 1.0494x over previous
//
#include <hip/hip_runtime.h>

#define N_NODES 50000
#define E_EDGES 800000
#define SCAN_NB 196   // 196*256 = 50176 >= N_NODES

// ============================ CSR build =====================================
__global__ __launch_bounds__(256) void k_hist(
    const int* __restrict__ ei, int* __restrict__ cnt)
{
    const int e = blockIdx.x * 256 + threadIdx.x;
    if (e < E_EDGES) atomicAdd(&cnt[ei[E_EDGES + e]], 1);
}

// ---- two-level parallel exclusive scan -------------------------------------
__global__ __launch_bounds__(256) void k_scan1(
    const int* __restrict__ cnt, int* __restrict__ bsum)
{
    __shared__ int red[256];
    const int tid = threadIdx.x;
    const int i = blockIdx.x * 256 + tid;
    red[tid] = (i < N_NODES) ? cnt[i] : 0;
    __syncthreads();
    for (int off = 128; off > 0; off >>= 1) {
        if (tid < off) red[tid] += red[tid + off];
        __syncthreads();
    }
    if (tid == 0) bsum[blockIdx.x] = red[0];
}

__global__ __launch_bounds__(256) void k_scan2(
    const int* __restrict__ bsum, int* __restrict__ boff)
{
    __shared__ int part[256];
    const int tid = threadIdx.x;
    const int v = (tid < SCAN_NB) ? bsum[tid] : 0;
    part[tid] = v;
    __syncthreads();
    for (int off = 1; off < 256; off <<= 1) {
        const int vv = part[tid];
        const int u = (tid >= off) ? part[tid - off] : 0;
        __syncthreads();
        part[tid] = vv + u;
        __syncthreads();
    }
    if (tid < SCAN_NB) boff[tid] = part[tid] - v;   // exclusive block offset
}

__global__ __launch_bounds__(256) void k_scan3(
    const int* __restrict__ cnt, const int* __restrict__ boff,
    int* __restrict__ rowptr, int* __restrict__ cursor)
{
    __shared__ int part[256];
    const int tid = threadIdx.x;
    const int i = blockIdx.x * 256 + tid;
    const int v = (i < N_NODES) ? cnt[i] : 0;
    part[tid] = v;
    __syncthreads();
    for (int off = 1; off < 256; off <<= 1) {
        const int vv = part[tid];
        const int u = (tid >= off) ? part[tid - off] : 0;
        __syncthreads();
        part[tid] = vv + u;
        __syncthreads();
    }
    const int excl = part[tid] - v + boff[blockIdx.x];
    if (i < N_NODES) { rowptr[i] = excl; cursor[i] = excl; }
    if (i == N_NODES) rowptr[N_NODES] = excl;  // beyond-end v=0 => excl = total
}

__global__ __launch_bounds__(256) void k_scatter(
    const int* __restrict__ ei, int* __restrict__ cursor, int2* __restrict__ pairs)
{
    const int e = blockIdx.x * 256 + threadIdx.x;
    if (e < E_EDGES) {
        const int dst = ei[E_EDGES + e];
        const int pos = atomicAdd(&cursor[dst], 1);
        pairs[pos] = make_int2(ei[e], e);
    }
}

// ============ CSR-order edge-attr pre-scale (kills gather deps) =============
__global__ __launch_bounds__(256) void k_prep(
    const int2* __restrict__ pairs, const float* __restrict__ eattr,
    const float* __restrict__ ew, float* __restrict__ eaw, int* __restrict__ srcs)
{
    const int t = blockIdx.x * 256 + threadIdx.x;
    const int pos = t >> 2;
    if (pos >= E_EDGES) return;
    const int q = t & 3;
    const int2 p = pairs[pos];
    if (q == 0) srcs[pos] = p.x;
    const float w = ew[p.y];
    const float4 a = *((const float4*)(eattr + (size_t)p.y * 16) + q);
    *((float4*)(eaw + (size_t)pos * 16) + q) =
        make_float4(a.x * w, a.y * w, a.z * w, a.w * w);
}

// ================== Weight transposes (once, tiny) ==========================
// WT segments (float offsets): WT11@0 [64][128], WT12@8192 [128][128],
// WT21@24576, WT22@40960, WTo@57344 [128][128] (j>=100 zero-padded),
// WeT1@73728 [16][64], WeT2@74752 [16][128].
__global__ __launch_bounds__(256) void k_wt(
    const float* __restrict__ W11, const float* __restrict__ W12,
    const float* __restrict__ W21, const float* __restrict__ W22,
    const float* __restrict__ Wo,
    const float* __restrict__ We1, const float* __restrict__ We2,
    float* __restrict__ WT)
{
    const int bid = blockIdx.x;
    const int tid = threadIdx.x;
    if (bid < 288) {
        const float* src; int KIN, JOUT, lbase, obase;
        if (bid < 32)       { src = W11; KIN = 64;  JOUT = 128; lbase = 0;   obase = 0; }
        else if (bid < 96)  { src = W12; KIN = 128; JOUT = 128; lbase = 32;  obase = 8192; }
        else if (bid < 160) { src = W21; KIN = 128; JOUT = 128; lbase = 96;  obase = 24576; }
        else if (bid < 224) { src = W22; KIN = 128; JOUT = 128; lbase = 160; obase = 40960; }
        else                { src = Wo;  KIN = 128; JOUT = 100; lbase = 224; obase = 57344; }
        const int idx = (bid - lbase) * 256 + tid;   // < KIN*128
        const int k = idx >> 7, j = idx & 127;
        WT[obase + idx] = (j < JOUT) ? src[j * KIN + k] : 0.f;
    } else if (bid < 292) {                   // WeT1[k][d] = We1[d][k]
        const int idx = (bid - 288) * 256 + tid;     // < 1024
        const int k = idx >> 6, d = idx & 63;
        WT[73728 + idx] = We1[d * 16 + k];
    } else {                                  // WeT2[k][d] = We2[d][k]
        const int idx = (bid - 292) * 256 + tid;     // < 2048
        const int k = idx >> 7, d = idx & 127;
        WT[74752 + idx] = We2[d * 16 + k];
    }
}

// ===================== Edge layer 1 (CSR gather, 16->64) ====================
// One wave per node; node wave-uniform (readfirstlane) so rp/srcs/eaw reads
// are s_load through the scalar pipe. 16 FMA + coalesced x-row read per edge.
__global__ __launch_bounds__(256, 4) void k_edge1(
    const int* __restrict__ rp, const int* __restrict__ srcs,
    const float* __restrict__ eaw,
    const float* __restrict__ WeT1, const float* __restrict__ be1,
    const float* __restrict__ x, float* __restrict__ out)
{
    const int lane = threadIdx.x & 63;
    const int node =
        __builtin_amdgcn_readfirstlane(blockIdx.x * 4 + (threadIdx.x >> 6));
    if (node >= N_NODES) return;

    float wr[16];
#pragma unroll
    for (int k = 0; k < 16; ++k) wr[k] = WeT1[k * 64 + lane];   // coalesced 256B
    const float bias = be1[lane];

    const int beg = rp[node], end = rp[node + 1];               // s_load
    float acc = 0.f;

#pragma unroll 4
    for (int c = beg; c < end; ++c) {
        const int src = srcs[c];                     // uniform -> s_load
        const float hv = x[(size_t)src * 64 + lane]; // coalesced row read
        const float* ep = eaw + (size_t)c * 16;      // uniform -> s_load x16
        float d = bias;
#pragma unroll
        for (int k = 0; k < 16; ++k) d = fmaf(ep[k], wr[k], d);
        acc += fmaxf(hv + d, 0.f);
    }
    out[(size_t)node * 64 + lane] = x[(size_t)node * 64 + lane] + acc;
}

// ===================== Edge layer 2 (CSR gather, 16->128) ===================
__global__ __launch_bounds__(256, 4) void k_edge2(
    const int* __restrict__ rp, const int* __restrict__ srcs,
    const float* __restrict__ eaw,
    const float* __restrict__ WeT2, const float* __restrict__ be2,
    const float* __restrict__ h, float* __restrict__ out)
{
    const int lane = threadIdx.x & 63;
    const int node =
        __builtin_amdgcn_readfirstlane(blockIdx.x * 4 + (threadIdx.x >> 6));
    if (node >= N_NODES) return;

    const int dA = 2 * lane;
    float wrA[16], wrB[16];
#pragma unroll
    for (int k = 0; k < 16; ++k) {
        const float2 w = *(const float2*)(WeT2 + k * 128 + dA);  // coalesced 512B
        wrA[k] = w.x; wrB[k] = w.y;
    }
    const float2 bv = *(const float2*)(be2 + dA);
    const float biasA = bv.x, biasB = bv.y;

    const int beg = rp[node], end = rp[node + 1];                // s_load
    float accA = 0.f, accB = 0.f;

    const float* hrow = h + dA;

#pragma unroll 4
    for (int c = beg; c < end; ++c) {
        const int src = srcs[c];                      // uniform -> s_load
        const float2 hv = *(const float2*)(hrow + (size_t)src * 128);
        const float* ep = eaw + (size_t)c * 16;       // uniform -> s_load x16
        float dA_ = biasA, dB_ = biasB;
#pragma unroll
        for (int k = 0; k < 16; ++k) {
            dA_ = fmaf(ep[k], wrA[k], dA_);
            dB_ = fmaf(ep[k], wrB[k], dB_);
        }
        accA += fmaxf(hv.x + dA_, 0.f);
        accB += fmaxf(hv.y + dB_, 0.f);
    }
    const float2 self = *(const float2*)(h + (size_t)node * 128 + dA);
    *(float2*)(out + (size_t)node * 128 + dA) =
        make_float2(self.x + accA, self.y + accB);
}

// ==================== Fused MLP chains (LDS-resident h) =====================
// R9 post-mortem: 1-node/lane stages were weight-stream latency-bound
// (32 FMA per 32-float fetch). Fix: restore R7 k_mlp's PROVEN engine —
// 2 nodes/lane (acc0/acc1, 64 FMA per fetch), NT=128, [.][129] pad —
// with a SINGLE in-place LDS buffer: all reads of stage k complete before
// the post-loop barrier, so the stage output overwrites the same buffer
// (write after barrier, barrier again before next stage reads).
// LDS = 128*129*4 = 66,048 B -> 2 blocks/CU (same occupancy as R7 k_mlp).

#define MLP_STAGE2(WTb, KIN, S, A0, A1)                                       \
    {                                                                         \
        _Pragma("unroll")                                                     \
        for (int m = 0; m < 32; ++m) { A0[m] = 0.f; A1[m] = 0.f; }            \
        float wc[32];                                                         \
        _Pragma("unroll")                                                     \
        for (int m = 0; m < 32; ++m) wc[m] = WTb[j0 + m];                     \
        float h0 = S[lane], h1 = S[lane + 64];                                \
        for (int k = 0; k < (KIN) - 1; ++k) {                                 \
            float wn[32];                                                     \
            _Pragma("unroll")                                                 \
            for (int m = 0; m < 32; ++m) wn[m] = WTb[(k + 1) * 128 + j0 + m]; \
            const float h0n = S[(k + 1) * 129 + lane];                        \
            const float h1n = S[(k + 1) * 129 + lane + 64];                   \
            _Pragma("unroll")                                                 \
            for (int m = 0; m < 32; ++m) {                                    \
                A0[m] = fmaf(h0, wc[m], A0[m]);                               \
                A1[m] = fmaf(h1, wc[m], A1[m]);                               \
            }                                                                 \
            _Pragma("unroll")                                                 \
            for (int m = 0; m < 32; ++m) wc[m] = wn[m];                       \
            h0 = h0n; h1 = h1n;                                               \
        }                                                                     \
        _Pragma("unroll")                                                     \
        for (int m = 0; m < 32; ++m) {                                        \
            A0[m] = fmaf(h0, wc[m], A0[m]);                                   \
            A1[m] = fmaf(h1, wc[m], A1[m]);                                   \
        }                                                                     \
    }

// stage 128-node tile of H (row-major, KIN cols) transposed into S[KIN][129]
#define MLP_TILE128(H, KIN, S)                                                \
    for (int idx = tid; idx < 128 * ((KIN) / 4); idx += 256) {                \
        const int q = idx & ((KIN) / 4 - 1);                                  \
        const int n = idx / ((KIN) / 4);                                      \
        const int ng = (base + n < N_NODES) ? (base + n) : (N_NODES - 1);     \
        const float4 v = *(const float4*)(H + (size_t)ng * (KIN) + 4 * q);    \
        S[(4 * q + 0) * 129 + n] = v.x;                                       \
        S[(4 * q + 1) * 129 + n] = v.y;                                       \
        S[(4 * q + 2) * 129 + n] = v.z;                                       \
        S[(4 * q + 3) * 129 + n] = v.w;                                       \
    }

// write stage result (relu) in place: rows j0..j0+31, cols lane & lane+64
#define MLP_WRITE_LDS(S, Bb, A0, A1)                                          \
    _Pragma("unroll")                                                         \
    for (int m = 0; m < 32; ++m) {                                            \
        const float bb = Bb[j0 + m];                                          \
        S[(j0 + m) * 129 + lane]      = fmaxf(A0[m] + bb, 0.f);               \
        S[(j0 + m) * 129 + lane + 64] = fmaxf(A1[m] + bb, 0.f);               \
    }

// h1pre(64) -> relu(W11) -> relu(W12) -> t1(128)
__global__ __launch_bounds__(256) void k_mlp2(
    const float* __restrict__ H, const float* __restrict__ WT11,
    const float* __restrict__ b11, const float* __restrict__ WT12,
    const float* __restrict__ b12, float* __restrict__ OUT)
{
    extern __shared__ float S[];           // [128][129] single in-place buffer
    const int tid  = threadIdx.x;
    const int lane = tid & 63;
    const int j0   = __builtin_amdgcn_readfirstlane(tid >> 6) * 32;
    const int base = blockIdx.x * 128;

    MLP_TILE128(H, 64, S);                 // input in rows 0..63
    __syncthreads();

    float acc0[32], acc1[32];
    MLP_STAGE2(WT11, 64, S, acc0, acc1);
    __syncthreads();                       // all reads done -> in-place write
    MLP_WRITE_LDS(S, b11, acc0, acc1);
    __syncthreads();

    MLP_STAGE2(WT12, 128, S, acc0, acc1);

    const int n0 = base + lane, n1 = base + lane + 64;
    if (n0 < N_NODES) {
        float* row = OUT + (size_t)n0 * 128 + j0;
#pragma unroll
        for (int g = 0; g < 8; ++g) {
            float4 v;
            v.x = fmaxf(acc0[4 * g + 0] + b12[j0 + 4 * g + 0], 0.f);
            v.y = fmaxf(acc0[4 * g + 1] + b12[j0 + 4 * g + 1], 0.f);
            v.z = fmaxf(acc0[4 * g + 2] + b12[j0 + 4 * g + 2], 0.f);
            v.w = fmaxf(acc0[4 * g + 3] + b12[j0 + 4 * g + 3], 0.f);
            *(float4*)(row + 4 * g) = v;
        }
    }
    if (n1 < N_NODES) {
        float* row = OUT + (size_t)n1 * 128 + j0;
#pragma unroll
        for (int g = 0; g < 8; ++g) {
            float4 v;
            v.x = fmaxf(acc1[4 * g + 0] + b12[j0 + 4 * g + 0], 0.f);
            v.y = fmaxf(acc1[4 * g + 1] + b12[j0 + 4 * g + 1], 0.f);
            v.z = fmaxf(acc1[4 * g + 2] + b12[j0 + 4 * g + 2], 0.f);
            v.w = fmaxf(acc1[4 * g + 3] + b12[j0 + 4 * g + 3], 0.f);
            *(float4*)(row + 4 * g) = v;
        }
    }
}

// h2pre(128) -> relu(W21) -> relu(W22) -> Wo -> out(100)
__global__ __launch_bounds__(256) void k_mlp3(
    const float* __restrict__ H, const float* __restrict__ WT21,
    const float* __restrict__ b21, const float* __restrict__ WT22,
    const float* __restrict__ b22, const float* __restrict__ WTo,
    const float* __restrict__ bo, float* __restrict__ OUT)
{
    extern __shared__ float S[];           // [128][129] single in-place buffer
    const int tid  = threadIdx.x;
    const int lane = tid & 63;
    const int j0   = __builtin_amdgcn_readfirstlane(tid >> 6) * 32;
    const int base = blockIdx.x * 128;

    MLP_TILE128(H, 128, S);
    __syncthreads();

    float acc0[32], acc1[32];
    MLP_STAGE2(WT21, 128, S, acc0, acc1);
    __syncthreads();
    MLP_WRITE_LDS(S, b21, acc0, acc1);
    __syncthreads();

    MLP_STAGE2(WT22, 128, S, acc0, acc1);
    __syncthreads();
    MLP_WRITE_LDS(S, b22, acc0, acc1);
    __syncthreads();

    MLP_STAGE2(WTo, 128, S, acc0, acc1);

    const int n0 = base + lane, n1 = base + lane + 64;
    if (n0 < N_NODES) {
        float* row = OUT + (size_t)n0 * 100;
#pragma unroll
        for (int g = 0; g < 8; ++g) {
            if (j0 + 4 * g < 100) {           // 100%4==0: full groups only
                float4 v;
                v.x = acc0[4 * g + 0] + bo[j0 + 4 * g + 0];
                v.y = acc0[4 * g + 1] + bo[j0 + 4 * g + 1];
                v.z = acc0[4 * g + 2] + bo[j0 + 4 * g + 2];
                v.w = acc0[4 * g + 3] + bo[j0 + 4 * g + 3];
                *(float4*)(row + j0 + 4 * g) = v;
            }
        }
    }
    if (n1 < N_NODES) {
        float* row = OUT + (size_t)n1 * 100;
#pragma unroll
        for (int g = 0; g < 8; ++g) {
            if (j0 + 4 * g < 100) {
                float4 v;
                v.x = acc1[4 * g + 0] + bo[j0 + 4 * g + 0];
                v.y = acc1[4 * g + 1] + bo[j0 + 4 * g + 1];
                v.z = acc1[4 * g + 2] + bo[j0 + 4 * g + 2];
                v.w = acc1[4 * g + 3] + bo[j0 + 4 * g + 3];
                *(float4*)(row + j0 + 4 * g) = v;
            }
        }
    }
}

// ============================================================================
// Workspace layout (peak 106,118,144 B), lifetimes packed:
//   [0,        204800)  rowptr            (build .. edge2)
//   [204800,  3404800)  srcs              (prep .. edge2)
//       cnt    @204800  (hist..scan, dead before srcs written)
//       cursor @409600  (scan..scatter, dead before srcs written)
//   [3404800, 54604800) eaw  51.2MB       (prep .. edge2)
//   [54604800,80204800) t1 (=h1) 25.6MB   (mlp2 .. edge2-in)
//       pairs @54604800 6.4MB             (scatter..prep, dead before t1)
//   [80204800,105804800) h2pre 25.6MB     (edge2-out .. mlp3)
//       h1pre @80204800 12.8MB            (edge1..mlp2, dead before h2pre)
//   [105804800,106116096) WT 311,296 B    (k_wt .. mlp3; incl WeT1/WeT2)
//   [106116096,106118144) bsum/boff 2KB   (scan only)
extern "C" void kernel_launch(void* const* d_in, const int* in_sizes, int n_in,
                              void* d_out, int out_size, void* d_ws, size_t ws_size,
                              hipStream_t stream) {
    const float* x     = (const float*)d_in[0];
    const int*   ei    = (const int*)  d_in[1];
    const float* eattr = (const float*)d_in[2];
    const float* ew    = (const float*)d_in[3];
    const float* We1   = (const float*)d_in[4];
    const float* be1   = (const float*)d_in[5];
    const float* W11   = (const float*)d_in[6];
    const float* b11   = (const float*)d_in[7];
    const float* W12   = (const float*)d_in[8];
    const float* b12   = (const float*)d_in[9];
    const float* We2   = (const float*)d_in[10];
    const float* be2   = (const float*)d_in[11];
    const float* W21   = (const float*)d_in[12];
    const float* b21   = (const float*)d_in[13];
    const float* W22   = (const float*)d_in[14];
    const float* b22   = (const float*)d_in[15];
    const float* Wo    = (const float*)d_in[16];
    const float* bo    = (const float*)d_in[17];
    float* out = (float*)d_out;

    char* ws = (char*)d_ws;
    int*   rowptr = (int*)  (ws + 0);
    int*   cnt    = (int*)  (ws + 204800);
    int*   cursor = (int*)  (ws + 409600);
    int*   srcs   = (int*)  (ws + 204800);     // overlays cnt+cursor (dead)
    float* eaw    = (float*)(ws + 3404800);    // 51.2 MB
    float* t1     = (float*)(ws + 54604800);   // 25.6 MB (h1 alias)
    int2*  pairs  = (int2*) (ws + 54604800);   // 6.4 MB, dead before t1 written
    float* h2pre  = (float*)(ws + 80204800);   // 25.6 MB
    float* h1pre  = (float*)(ws + 80204800);   // 12.8 MB, dead before h2pre
    float* WT     = (float*)(ws + 105804800);  // 311,296 B
    float* WT11 = WT;           // [64][128]
    float* WT12 = WT + 8192;    // [128][128]
    float* WT21 = WT + 24576;
    float* WT22 = WT + 40960;
    float* WTo  = WT + 57344;   // [128][128] zero-padded j>=100
    float* WeT1 = WT + 73728;   // [16][64]
    float* WeT2 = WT + 74752;   // [16][128]
    int*   bsum = (int*)(ws + 106116096);      // 196 ints (pad 1KB)
    int*   boff = (int*)(ws + 106117120);      // 196 ints

    hipMemsetAsync(cnt, 0, 200000, stream);

    k_wt<<<300, 256, 0, stream>>>(W11, W12, W21, W22, Wo, We1, We2, WT);

    const int EB = (E_EDGES + 255) / 256;      // 3125
    k_hist<<<EB, 256, 0, stream>>>(ei, cnt);
    k_scan1<<<SCAN_NB, 256, 0, stream>>>(cnt, bsum);
    k_scan2<<<1, 256, 0, stream>>>(bsum, boff);
    k_scan3<<<SCAN_NB, 256, 0, stream>>>(cnt, boff, rowptr, cursor);
    k_scatter<<<EB, 256, 0, stream>>>(ei, cursor, pairs);

    const int PB = (E_EDGES * 4 + 255) / 256;  // 12500
    k_prep<<<PB, 256, 0, stream>>>(pairs, eattr, ew, eaw, srcs);

    const int NB = (N_NODES + 3) / 4;          // 12500 (one wave per node)
    k_edge1<<<NB, 256, 0, stream>>>(rowptr, srcs, eaw, WeT1, be1, x, h1pre);

    const int MB = (N_NODES + 127) / 128;      // 391
    const size_t ldsS = (size_t)(128 * 129) * 4;   // 66,048 B -> 2 blocks/CU

    k_mlp2<<<MB, 256, ldsS, stream>>>(h1pre, WT11, b11, WT12, b12, t1);

    k_edge2<<<NB, 256, 0, stream>>>(rowptr, srcs, eaw, WeT2, be2, t1, h2pre);

    k_mlp3<<<MB, 256, ldsS, stream>>>(h2pre, WT21, b21, WT22, b22, WTo, bo, out);
}

// Round 11
// 501.792 us; speedup vs baseline: 1.3837x; 1.0461x over previous
//
#include <hip/hip_runtime.h>

#define N_NODES 50000
#define E_EDGES 800000
#define SCAN_NB 196   // 196*256 = 50176 >= N_NODES

// ============================ CSR build =====================================
__global__ __launch_bounds__(256) void k_hist(
    const int* __restrict__ ei, int* __restrict__ cnt)
{
    const int e = blockIdx.x * 256 + threadIdx.x;
    if (e < E_EDGES) atomicAdd(&cnt[ei[E_EDGES + e]], 1);
}

// ---- two-level parallel exclusive scan -------------------------------------
__global__ __launch_bounds__(256) void k_scan1(
    const int* __restrict__ cnt, int* __restrict__ bsum)
{
    __shared__ int red[256];
    const int tid = threadIdx.x;
    const int i = blockIdx.x * 256 + tid;
    red[tid] = (i < N_NODES) ? cnt[i] : 0;
    __syncthreads();
    for (int off = 128; off > 0; off >>= 1) {
        if (tid < off) red[tid] += red[tid + off];
        __syncthreads();
    }
    if (tid == 0) bsum[blockIdx.x] = red[0];
}

__global__ __launch_bounds__(256) void k_scan2(
    const int* __restrict__ bsum, int* __restrict__ boff)
{
    __shared__ int part[256];
    const int tid = threadIdx.x;
    const int v = (tid < SCAN_NB) ? bsum[tid] : 0;
    part[tid] = v;
    __syncthreads();
    for (int off = 1; off < 256; off <<= 1) {
        const int vv = part[tid];
        const int u = (tid >= off) ? part[tid - off] : 0;
        __syncthreads();
        part[tid] = vv + u;
        __syncthreads();
    }
    if (tid < SCAN_NB) boff[tid] = part[tid] - v;   // exclusive block offset
}

__global__ __launch_bounds__(256) void k_scan3(
    const int* __restrict__ cnt, const int* __restrict__ boff,
    int* __restrict__ rowptr, int* __restrict__ cursor)
{
    __shared__ int part[256];
    const int tid = threadIdx.x;
    const int i = blockIdx.x * 256 + tid;
    const int v = (i < N_NODES) ? cnt[i] : 0;
    part[tid] = v;
    __syncthreads();
    for (int off = 1; off < 256; off <<= 1) {
        const int vv = part[tid];
        const int u = (tid >= off) ? part[tid - off] : 0;
        __syncthreads();
        part[tid] = vv + u;
        __syncthreads();
    }
    const int excl = part[tid] - v + boff[blockIdx.x];
    if (i < N_NODES) { rowptr[i] = excl; cursor[i] = excl; }
    if (i == N_NODES) rowptr[N_NODES] = excl;  // beyond-end v=0 => excl = total
}

__global__ __launch_bounds__(256) void k_scatter(
    const int* __restrict__ ei, int* __restrict__ cursor, int2* __restrict__ pairs)
{
    const int e = blockIdx.x * 256 + threadIdx.x;
    if (e < E_EDGES) {
        const int dst = ei[E_EDGES + e];
        const int pos = atomicAdd(&cursor[dst], 1);
        pairs[pos] = make_int2(ei[e], e);
    }
}

// ============ CSR-order edge-attr pre-scale (kills gather deps) =============
__global__ __launch_bounds__(256) void k_prep(
    const int2* __restrict__ pairs, const float* __restrict__ eattr,
    const float* __restrict__ ew, float* __restrict__ eaw, int* __restrict__ srcs)
{
    const int t = blockIdx.x * 256 + threadIdx.x;
    const int pos = t >> 2;
    if (pos >= E_EDGES) return;
    const int q = t & 3;
    const int2 p = pairs[pos];
    if (q == 0) srcs[pos] = p.x;
    const float w = ew[p.y];
    const float4 a = *((const float4*)(eattr + (size_t)p.y * 16) + q);
    *((float4*)(eaw + (size_t)pos * 16) + q) =
        make_float4(a.x * w, a.y * w, a.z * w, a.w * w);
}

// ================== Weight transposes (once, tiny) ==========================
// WT segments (float offsets): WT11@0 [64][128], WT12@8192 [128][128],
// WT21@24576, WT22@40960, WTo@57344 [128][128] (j>=100 zero-padded),
// WeT1@73728 [16][64], WeT2@74752 [16][128].
__global__ __launch_bounds__(256) void k_wt(
    const float* __restrict__ W11, const float* __restrict__ W12,
    const float* __restrict__ W21, const float* __restrict__ W22,
    const float* __restrict__ Wo,
    const float* __restrict__ We1, const float* __restrict__ We2,
    float* __restrict__ WT)
{
    const int bid = blockIdx.x;
    const int tid = threadIdx.x;
    if (bid < 288) {
        const float* src; int KIN, JOUT, lbase, obase;
        if (bid < 32)       { src = W11; KIN = 64;  JOUT = 128; lbase = 0;   obase = 0; }
        else if (bid < 96)  { src = W12; KIN = 128; JOUT = 128; lbase = 32;  obase = 8192; }
        else if (bid < 160) { src = W21; KIN = 128; JOUT = 128; lbase = 96;  obase = 24576; }
        else if (bid < 224) { src = W22; KIN = 128; JOUT = 128; lbase = 160; obase = 40960; }
        else                { src = Wo;  KIN = 128; JOUT = 100; lbase = 224; obase = 57344; }
        const int idx = (bid - lbase) * 256 + tid;   // < KIN*128
        const int k = idx >> 7, j = idx & 127;
        WT[obase + idx] = (j < JOUT) ? src[j * KIN + k] : 0.f;
    } else if (bid < 292) {                   // WeT1[k][d] = We1[d][k]
        const int idx = (bid - 288) * 256 + tid;     // < 1024
        const int k = idx >> 6, d = idx & 63;
        WT[73728 + idx] = We1[d * 16 + k];
    } else {                                  // WeT2[k][d] = We2[d][k]
        const int idx = (bid - 292) * 256 + tid;     // < 2048
        const int k = idx >> 7, d = idx & 127;
        WT[74752 + idx] = We2[d * 16 + k];
    }
}

// ===================== Edge layer 1 (CSR gather, 16->64) ====================
// One wave per node; node wave-uniform (readfirstlane) so rp/srcs/eaw reads
// are s_load through the scalar pipe. 16 FMA + coalesced x-row read per edge.
__global__ __launch_bounds__(256, 4) void k_edge1(
    const int* __restrict__ rp, const int* __restrict__ srcs,
    const float* __restrict__ eaw,
    const float* __restrict__ WeT1, const float* __restrict__ be1,
    const float* __restrict__ x, float* __restrict__ out)
{
    const int lane = threadIdx.x & 63;
    const int node =
        __builtin_amdgcn_readfirstlane(blockIdx.x * 4 + (threadIdx.x >> 6));
    if (node >= N_NODES) return;

    float wr[16];
#pragma unroll
    for (int k = 0; k < 16; ++k) wr[k] = WeT1[k * 64 + lane];   // coalesced 256B
    const float bias = be1[lane];

    const int beg = rp[node], end = rp[node + 1];               // s_load
    float acc = 0.f;

#pragma unroll 4
    for (int c = beg; c < end; ++c) {
        const int src = srcs[c];                     // uniform -> s_load
        const float hv = x[(size_t)src * 64 + lane]; // coalesced row read
        const float* ep = eaw + (size_t)c * 16;      // uniform -> s_load x16
        float d = bias;
#pragma unroll
        for (int k = 0; k < 16; ++k) d = fmaf(ep[k], wr[k], d);
        acc += fmaxf(hv + d, 0.f);
    }
    out[(size_t)node * 64 + lane] = x[(size_t)node * 64 + lane] + acc;
}

// ===================== Edge layer 2 (CSR gather, 16->128) ===================
__global__ __launch_bounds__(256, 4) void k_edge2(
    const int* __restrict__ rp, const int* __restrict__ srcs,
    const float* __restrict__ eaw,
    const float* __restrict__ WeT2, const float* __restrict__ be2,
    const float* __restrict__ h, float* __restrict__ out)
{
    const int lane = threadIdx.x & 63;
    const int node =
        __builtin_amdgcn_readfirstlane(blockIdx.x * 4 + (threadIdx.x >> 6));
    if (node >= N_NODES) return;

    const int dA = 2 * lane;
    float wrA[16], wrB[16];
#pragma unroll
    for (int k = 0; k < 16; ++k) {
        const float2 w = *(const float2*)(WeT2 + k * 128 + dA);  // coalesced 512B
        wrA[k] = w.x; wrB[k] = w.y;
    }
    const float2 bv = *(const float2*)(be2 + dA);
    const float biasA = bv.x, biasB = bv.y;

    const int beg = rp[node], end = rp[node + 1];                // s_load
    float accA = 0.f, accB = 0.f;

    const float* hrow = h + dA;

#pragma unroll 4
    for (int c = beg; c < end; ++c) {
        const int src = srcs[c];                      // uniform -> s_load
        const float2 hv = *(const float2*)(hrow + (size_t)src * 128);
        const float* ep = eaw + (size_t)c * 16;       // uniform -> s_load x16
        float dA_ = biasA, dB_ = biasB;
#pragma unroll
        for (int k = 0; k < 16; ++k) {
            dA_ = fmaf(ep[k], wrA[k], dA_);
            dB_ = fmaf(ep[k], wrB[k], dB_);
        }
        accA += fmaxf(hv.x + dA_, 0.f);
        accB += fmaxf(hv.y + dB_, 0.f);
    }
    const float2 self = *(const float2*)(h + (size_t)node * 128 + dA);
    *(float2*)(out + (size_t)node * 128 + dA) =
        make_float2(self.x + accA, self.y + accB);
}

// ==================== Fused MLP chains (LDS-resident h) =====================
// R10 post-mortem: 256-thread blocks at 66KB LDS = 8 waves/CU (25% cap) and
// 391 blocks/256 CUs = 1.5 generations (tail) -> measured 16% occupancy,
// weight-stream latency exposed. Fix: 512-thread blocks (8 waves), wave wv
// owns (j0=(wv&3)*32, node-half nb=(wv>>2)*64), lane owns 1 node. Same 66KB
// LDS -> 2 blocks/CU but 16 waves/CU (50%), and 391 blocks <= 512 resident
// slots -> entire grid co-resident, zero tail. 4 waves/SIMD hide the s_load
// weight bursts. __launch_bounds__(512,4) caps VGPR at 128 (need ~100).

#define MLP_STAGE1(WTb, KIN, S, ACC)                                          \
    {                                                                         \
        _Pragma("unroll")                                                     \
        for (int m = 0; m < 32; ++m) ACC[m] = 0.f;                            \
        float wc[32];                                                         \
        _Pragma("unroll")                                                     \
        for (int m = 0; m < 32; ++m) wc[m] = WTb[j0 + m];                     \
        float h0 = S[nb + lane];                                              \
        for (int k = 0; k < (KIN) - 1; ++k) {                                 \
            float wn[32];                                                     \
            _Pragma("unroll")                                                 \
            for (int m = 0; m < 32; ++m) wn[m] = WTb[(k + 1) * 128 + j0 + m]; \
            const float h0n = S[(k + 1) * 129 + nb + lane];                   \
            _Pragma("unroll")                                                 \
            for (int m = 0; m < 32; ++m) ACC[m] = fmaf(h0, wc[m], ACC[m]);    \
            _Pragma("unroll")                                                 \
            for (int m = 0; m < 32; ++m) wc[m] = wn[m];                       \
            h0 = h0n;                                                         \
        }                                                                     \
        _Pragma("unroll")                                                     \
        for (int m = 0; m < 32; ++m) ACC[m] = fmaf(h0, wc[m], ACC[m]);        \
    }

// stage 128-node tile of H (row-major, KIN cols) transposed into S[KIN][129]
#define MLP_TILE128(H, KIN, S)                                                \
    for (int idx = tid; idx < 128 * ((KIN) / 4); idx += 512) {                \
        const int q = idx & ((KIN) / 4 - 1);                                  \
        const int n = idx / ((KIN) / 4);                                      \
        const int ng = (base + n < N_NODES) ? (base + n) : (N_NODES - 1);     \
        const float4 v = *(const float4*)(H + (size_t)ng * (KIN) + 4 * q);    \
        S[(4 * q + 0) * 129 + n] = v.x;                                       \
        S[(4 * q + 1) * 129 + n] = v.y;                                       \
        S[(4 * q + 2) * 129 + n] = v.z;                                       \
        S[(4 * q + 3) * 129 + n] = v.w;                                       \
    }

// write stage result (relu) in place: rows j0..j0+31, col nb+lane
#define MLP_WRITE_LDS(S, Bb, ACC)                                             \
    _Pragma("unroll")                                                         \
    for (int m = 0; m < 32; ++m)                                              \
        S[(j0 + m) * 129 + nb + lane] = fmaxf(ACC[m] + Bb[j0 + m], 0.f);

// h1pre(64) -> relu(W11) -> relu(W12) -> t1(128)
__global__ __launch_bounds__(512, 4) void k_mlp2(
    const float* __restrict__ H, const float* __restrict__ WT11,
    const float* __restrict__ b11, const float* __restrict__ WT12,
    const float* __restrict__ b12, float* __restrict__ OUT)
{
    extern __shared__ float S[];           // [128][129] single in-place buffer
    const int tid  = threadIdx.x;
    const int lane = tid & 63;
    const int wv   = __builtin_amdgcn_readfirstlane(tid >> 6);
    const int j0   = (wv & 3) * 32;
    const int nb   = (wv >> 2) * 64;
    const int base = blockIdx.x * 128;

    MLP_TILE128(H, 64, S);                 // input in rows 0..63
    __syncthreads();

    float acc[32];
    MLP_STAGE1(WT11, 64, S, acc);
    __syncthreads();                       // all reads done -> in-place write
    MLP_WRITE_LDS(S, b11, acc);
    __syncthreads();

    MLP_STAGE1(WT12, 128, S, acc);

    const int node = base + nb + lane;
    if (node < N_NODES) {
        float* row = OUT + (size_t)node * 128 + j0;
#pragma unroll
        for (int g = 0; g < 8; ++g) {
            float4 v;
            v.x = fmaxf(acc[4 * g + 0] + b12[j0 + 4 * g + 0], 0.f);
            v.y = fmaxf(acc[4 * g + 1] + b12[j0 + 4 * g + 1], 0.f);
            v.z = fmaxf(acc[4 * g + 2] + b12[j0 + 4 * g + 2], 0.f);
            v.w = fmaxf(acc[4 * g + 3] + b12[j0 + 4 * g + 3], 0.f);
            *(float4*)(row + 4 * g) = v;
        }
    }
}

// h2pre(128) -> relu(W21) -> relu(W22) -> Wo -> out(100)
__global__ __launch_bounds__(512, 4) void k_mlp3(
    const float* __restrict__ H, const float* __restrict__ WT21,
    const float* __restrict__ b21, const float* __restrict__ WT22,
    const float* __restrict__ b22, const float* __restrict__ WTo,
    const float* __restrict__ bo, float* __restrict__ OUT)
{
    extern __shared__ float S[];           // [128][129] single in-place buffer
    const int tid  = threadIdx.x;
    const int lane = tid & 63;
    const int wv   = __builtin_amdgcn_readfirstlane(tid >> 6);
    const int j0   = (wv & 3) * 32;
    const int nb   = (wv >> 2) * 64;
    const int base = blockIdx.x * 128;

    MLP_TILE128(H, 128, S);
    __syncthreads();

    float acc[32];
    MLP_STAGE1(WT21, 128, S, acc);
    __syncthreads();
    MLP_WRITE_LDS(S, b21, acc);
    __syncthreads();

    MLP_STAGE1(WT22, 128, S, acc);
    __syncthreads();
    MLP_WRITE_LDS(S, b22, acc);
    __syncthreads();

    MLP_STAGE1(WTo, 128, S, acc);

    const int node = base + nb + lane;
    if (node < N_NODES) {
        float* row = OUT + (size_t)node * 100;
#pragma unroll
        for (int g = 0; g < 8; ++g) {
            if (j0 + 4 * g < 100) {           // 100%4==0: full groups only
                float4 v;
                v.x = acc[4 * g + 0] + bo[j0 + 4 * g + 0];
                v.y = acc[4 * g + 1] + bo[j0 + 4 * g + 1];
                v.z = acc[4 * g + 2] + bo[j0 + 4 * g + 2];
                v.w = acc[4 * g + 3] + bo[j0 + 4 * g + 3];
                *(float4*)(row + j0 + 4 * g) = v;
            }
        }
    }
}

// ============================================================================
// Workspace layout (peak 106,118,144 B), lifetimes packed:
//   [0,        204800)  rowptr            (build .. edge2)
//   [204800,  3404800)  srcs              (prep .. edge2)
//       cnt    @204800  (hist..scan, dead before srcs written)
//       cursor @409600  (scan..scatter, dead before srcs written)
//   [3404800, 54604800) eaw  51.2MB       (prep .. edge2)
//   [54604800,80204800) t1 (=h1) 25.6MB   (mlp2 .. edge2-in)
//       pairs @54604800 6.4MB             (scatter..prep, dead before t1)
//   [80204800,105804800) h2pre 25.6MB     (edge2-out .. mlp3)
//       h1pre @80204800 12.8MB            (edge1..mlp2, dead before h2pre)
//   [105804800,106116096) WT 311,296 B    (k_wt .. mlp3; incl WeT1/WeT2)
//   [106116096,106118144) bsum/boff 2KB   (scan only)
extern "C" void kernel_launch(void* const* d_in, const int* in_sizes, int n_in,
                              void* d_out, int out_size, void* d_ws, size_t ws_size,
                              hipStream_t stream) {
    const float* x     = (const float*)d_in[0];
    const int*   ei    = (const int*)  d_in[1];
    const float* eattr = (const float*)d_in[2];
    const float* ew    = (const float*)d_in[3];
    const float* We1   = (const float*)d_in[4];
    const float* be1   = (const float*)d_in[5];
    const float* W11   = (const float*)d_in[6];
    const float* b11   = (const float*)d_in[7];
    const float* W12   = (const float*)d_in[8];
    const float* b12   = (const float*)d_in[9];
    const float* We2   = (const float*)d_in[10];
    const float* be2   = (const float*)d_in[11];
    const float* W21   = (const float*)d_in[12];
    const float* b21   = (const float*)d_in[13];
    const float* W22   = (const float*)d_in[14];
    const float* b22   = (const float*)d_in[15];
    const float* Wo    = (const float*)d_in[16];
    const float* bo    = (const float*)d_in[17];
    float* out = (float*)d_out;

    char* ws = (char*)d_ws;
    int*   rowptr = (int*)  (ws + 0);
    int*   cnt    = (int*)  (ws + 204800);
    int*   cursor = (int*)  (ws + 409600);
    int*   srcs   = (int*)  (ws + 204800);     // overlays cnt+cursor (dead)
    float* eaw    = (float*)(ws + 3404800);    // 51.2 MB
    float* t1     = (float*)(ws + 54604800);   // 25.6 MB (h1 alias)
    int2*  pairs  = (int2*) (ws + 54604800);   // 6.4 MB, dead before t1 written
    float* h2pre  = (float*)(ws + 80204800);   // 25.6 MB
    float* h1pre  = (float*)(ws + 80204800);   // 12.8 MB, dead before h2pre
    float* WT     = (float*)(ws + 105804800);  // 311,296 B
    float* WT11 = WT;           // [64][128]
    float* WT12 = WT + 8192;    // [128][128]
    float* WT21 = WT + 24576;
    float* WT22 = WT + 40960;
    float* WTo  = WT + 57344;   // [128][128] zero-padded j>=100
    float* WeT1 = WT + 73728;   // [16][64]
    float* WeT2 = WT + 74752;   // [16][128]
    int*   bsum = (int*)(ws + 106116096);      // 196 ints (pad 1KB)
    int*   boff = (int*)(ws + 106117120);      // 196 ints

    hipMemsetAsync(cnt, 0, 200000, stream);

    k_wt<<<300, 256, 0, stream>>>(W11, W12, W21, W22, Wo, We1, We2, WT);

    const int EB = (E_EDGES + 255) / 256;      // 3125
    k_hist<<<EB, 256, 0, stream>>>(ei, cnt);
    k_scan1<<<SCAN_NB, 256, 0, stream>>>(cnt, bsum);
    k_scan2<<<1, 256, 0, stream>>>(bsum, boff);
    k_scan3<<<SCAN_NB, 256, 0, stream>>>(cnt, boff, rowptr, cursor);
    k_scatter<<<EB, 256, 0, stream>>>(ei, cursor, pairs);

    const int PB = (E_EDGES * 4 + 255) / 256;  // 12500
    k_prep<<<PB, 256, 0, stream>>>(pairs, eattr, ew, eaw, srcs);

    const int NB = (N_NODES + 3) / 4;          // 12500 (one wave per node)
    k_edge1<<<NB, 256, 0, stream>>>(rowptr, srcs, eaw, WeT1, be1, x, h1pre);

    const int MB = (N_NODES + 127) / 128;      // 391
    const size_t ldsS = (size_t)(128 * 129) * 4;   // 66,048 B -> 2 blocks/CU

    k_mlp2<<<MB, 512, ldsS, stream>>>(h1pre, WT11, b11, WT12, b12, t1);

    k_edge2<<<NB, 256, 0, stream>>>(rowptr, srcs, eaw, WeT2, be2, t1, h2pre);

    k_mlp3<<<MB, 512, ldsS, stream>>>(h2pre, WT21, b21, WT22, b22, WTo, bo, out);
}